// Round 1
// baseline (107.063 us; speedup 1.0000x reference)
//
#include <hip/hip_runtime.h>
#include <math.h>

#define NEG_SLOPE 0.01f

// Kernel 1: per-node dot products  a_src[n] = h[n,:]·w[:F],  a_dst[n] = h[n,:]·w[F:]
// One wave (64 lanes) per node; lane = feature index (F == 64).
__global__ void node_dots(const float* __restrict__ h, const float* __restrict__ w,
                          float* __restrict__ a_src, float* __restrict__ a_dst, int N) {
    int wid  = (int)((blockIdx.x * blockDim.x + threadIdx.x) >> 6);
    int lane = threadIdx.x & 63;
    if (wid >= N) return;
    float hv = h[wid * 64 + lane];
    float ps = hv * w[lane];
    float pd = hv * w[64 + lane];
    #pragma unroll
    for (int o = 32; o; o >>= 1) {
        ps += __shfl_xor(ps, o);
        pd += __shfl_xor(pd, o);
    }
    if (lane == 0) { a_src[wid] = ps; a_dst[wid] = pd; }
}

// Kernel 2: segment starts via lower_bound over sorted dst.
// seg[n] = first edge index with dst[i] >= n; seg[N] = E.
__global__ void seg_starts(const int* __restrict__ dst, int* __restrict__ seg,
                           int N, int E) {
    int t = blockIdx.x * blockDim.x + threadIdx.x;
    if (t > N) return;
    if (t == N) { seg[N] = E; return; }
    int lo = 0, hi = E;
    while (lo < hi) {
        int mid = (lo + hi) >> 1;
        if (dst[mid] < t) lo = mid + 1; else hi = mid;
    }
    seg[t] = lo;
}

// Kernel 3: one wave per dst node. Segment edges are contiguous [seg[n], seg[n+1]).
// Pass 1: lane-parallel max of leaky(e); Pass 2: lane-parallel sum of exp(e-m);
// Pass 3: serial over edges, lane f accumulates alpha_i * h[src_i][f] (coalesced row read).
__global__ void gat_out(const float* __restrict__ h, const float* __restrict__ a_src,
                        const float* __restrict__ a_dst, const int* __restrict__ src,
                        const int* __restrict__ seg, float* __restrict__ out, int N) {
    int wid  = (int)((blockIdx.x * blockDim.x + threadIdx.x) >> 6);
    int lane = threadIdx.x & 63;
    if (wid >= N) return;
    int s    = seg[wid];
    int eend = seg[wid + 1];
    if (eend <= s) {            // empty segment -> zero row (matches segment_sum of nothing)
        out[wid * 64 + lane] = 0.0f;
        return;
    }
    float ad = a_dst[wid];

    // Pass 1: segment max
    float m = -INFINITY;
    for (int i = s + lane; i < eend; i += 64) {
        float e = a_src[src[i]] + ad;
        e = (e >= 0.0f) ? e : NEG_SLOPE * e;
        m = fmaxf(m, e);
    }
    #pragma unroll
    for (int o = 32; o; o >>= 1) m = fmaxf(m, __shfl_xor(m, o));

    // Pass 2: denom = sum exp(e - m)
    float dsum = 0.0f;
    for (int i = s + lane; i < eend; i += 64) {
        float e = a_src[src[i]] + ad;
        e = (e >= 0.0f) ? e : NEG_SLOPE * e;
        dsum += __expf(e - m);
    }
    #pragma unroll
    for (int o = 32; o; o >>= 1) dsum += __shfl_xor(dsum, o);
    float inv = 1.0f / dsum;

    // Pass 3: weighted scatter-sum (serial over segment edges -> deterministic)
    float acc = 0.0f;
    for (int i = s; i < eend; ++i) {
        int   sj    = src[i];                    // wave-uniform broadcast load
        float e     = a_src[sj] + ad;
        e = (e >= 0.0f) ? e : NEG_SLOPE * e;
        float alpha = __expf(e - m) * inv;
        acc = fmaf(alpha, h[sj * 64 + lane], acc);  // coalesced 256B row read
    }
    out[wid * 64 + lane] = acc;
}

extern "C" void kernel_launch(void* const* d_in, const int* in_sizes, int n_in,
                              void* d_out, int out_size, void* d_ws, size_t ws_size,
                              hipStream_t stream) {
    const float* h   = (const float*)d_in[0];
    const float* w   = (const float*)d_in[1];
    const int*   src = (const int*)d_in[2];
    const int*   dst = (const int*)d_in[3];
    float*       out = (float*)d_out;

    const int F = in_sizes[1] / 2;       // 64
    const int N = in_sizes[0] / F;       // 50000
    const int E = in_sizes[2];           // 800000

    float* a_src = (float*)d_ws;
    float* a_dst = a_src + N;
    int*   seg   = (int*)(a_dst + N);    // N+1 ints

    // 4 waves (nodes) per 256-thread block
    node_dots<<<dim3((N + 3) / 4), dim3(256), 0, stream>>>(h, w, a_src, a_dst, N);
    seg_starts<<<dim3((N + 1 + 255) / 256), dim3(256), 0, stream>>>(dst, seg, N, E);
    gat_out<<<dim3((N + 3) / 4), dim3(256), 0, stream>>>(h, a_src, a_dst, src, seg, out, N);
}

// Round 2
// 76.564 us; speedup vs baseline: 1.3983x; 1.3983x over previous
//
#include <hip/hip_runtime.h>
#include <math.h>

#define NEG_SLOPE 0.01f

// Kernel 1: per-node dot products  a_src[n] = h[n,:]·w[:F],  a_dst[n] = h[n,:]·w[F:]
// One wave (64 lanes) per node; lane = feature index (F == 64).
__global__ void node_dots(const float* __restrict__ h, const float* __restrict__ w,
                          float* __restrict__ a_src, float* __restrict__ a_dst, int N) {
    int wid  = (int)((blockIdx.x * blockDim.x + threadIdx.x) >> 6);
    int lane = threadIdx.x & 63;
    if (wid >= N) return;
    float hv = h[wid * 64 + lane];
    float ps = hv * w[lane];
    float pd = hv * w[64 + lane];
    #pragma unroll
    for (int o = 32; o; o >>= 1) {
        ps += __shfl_xor(ps, o);
        pd += __shfl_xor(pd, o);
    }
    if (lane == 0) { a_src[wid] = ps; a_dst[wid] = pd; }
}

// Kernel 2: segment starts via lower_bound over sorted dst.
__global__ void seg_starts(const int* __restrict__ dst, int* __restrict__ seg,
                           int N, int E) {
    int t = blockIdx.x * blockDim.x + threadIdx.x;
    if (t > N) return;
    if (t == N) { seg[N] = E; return; }
    int lo = 0, hi = E;
    while (lo < hi) {
        int mid = (lo + hi) >> 1;
        if (dst[mid] < t) lo = mid + 1; else hi = mid;
    }
    seg[t] = lo;
}

// Kernel 3: one wave per dst node.
// Fast path (deg<=64, ~always for Poisson(16)): lane l owns edge s+l.
//   One parallel a_src gather, shfl-reduce max & denom, alpha stays in register.
//   Accumulation: broadcast (alpha_j, src_j) via shfl; each edge is one coalesced
//   256B h-row read + fmaf; unroll 8 keeps ~8 gathers in flight.
__global__ void gat_out(const float* __restrict__ h, const float* __restrict__ a_src,
                        const float* __restrict__ a_dst, const int* __restrict__ src,
                        const int* __restrict__ seg, float* __restrict__ out, int N) {
    int wid  = (int)((blockIdx.x * blockDim.x + threadIdx.x) >> 6);
    int lane = threadIdx.x & 63;
    if (wid >= N) return;
    int s    = seg[wid];
    int eend = seg[wid + 1];
    int deg  = eend - s;
    if (deg <= 0) { out[wid * 64 + lane] = 0.0f; return; }
    float ad = a_dst[wid];

    if (deg <= 64) {
        bool v  = (lane < deg);
        int  sj = v ? src[s + lane] : 0;
        float e = a_src[sj] + ad;               // sj=0 for invalid lanes: safe load
        e = (e >= 0.0f) ? e : NEG_SLOPE * e;
        if (!v) e = -INFINITY;

        float m = e;
        #pragma unroll
        for (int o = 32; o; o >>= 1) m = fmaxf(m, __shfl_xor(m, o));

        float p = v ? __expf(e - m) : 0.0f;
        float dsum = p;
        #pragma unroll
        for (int o = 32; o; o >>= 1) dsum += __shfl_xor(dsum, o);
        p *= (1.0f / dsum);                     // p = alpha for this lane's edge

        float acc = 0.0f;
        const float* hl = h + lane;
        #pragma unroll 8
        for (int j = 0; j < deg; ++j) {
            float aj  = __shfl(p, j);
            int   sjj = __shfl(sj, j);
            acc = fmaf(aj, hl[(long)sjj * 64], acc);
        }
        out[wid * 64 + lane] = acc;
    } else {
        // Rare fallback: 3-pass chunked, serial accumulation (deterministic).
        float m = -INFINITY;
        for (int i = s + lane; i < eend; i += 64) {
            float e = a_src[src[i]] + ad;
            e = (e >= 0.0f) ? e : NEG_SLOPE * e;
            m = fmaxf(m, e);
        }
        #pragma unroll
        for (int o = 32; o; o >>= 1) m = fmaxf(m, __shfl_xor(m, o));

        float dsum = 0.0f;
        for (int i = s + lane; i < eend; i += 64) {
            float e = a_src[src[i]] + ad;
            e = (e >= 0.0f) ? e : NEG_SLOPE * e;
            dsum += __expf(e - m);
        }
        #pragma unroll
        for (int o = 32; o; o >>= 1) dsum += __shfl_xor(dsum, o);
        float inv = 1.0f / dsum;

        float acc = 0.0f;
        for (int i = s; i < eend; ++i) {
            int   sj    = src[i];
            float e     = a_src[sj] + ad;
            e = (e >= 0.0f) ? e : NEG_SLOPE * e;
            float alpha = __expf(e - m) * inv;
            acc = fmaf(alpha, h[(long)sj * 64 + lane], acc);
        }
        out[wid * 64 + lane] = acc;
    }
}

extern "C" void kernel_launch(void* const* d_in, const int* in_sizes, int n_in,
                              void* d_out, int out_size, void* d_ws, size_t ws_size,
                              hipStream_t stream) {
    const float* h   = (const float*)d_in[0];
    const float* w   = (const float*)d_in[1];
    const int*   src = (const int*)d_in[2];
    const int*   dst = (const int*)d_in[3];
    float*       out = (float*)d_out;

    const int F = in_sizes[1] / 2;       // 64
    const int N = in_sizes[0] / F;       // 50000
    const int E = in_sizes[2];           // 800000

    float* a_src = (float*)d_ws;
    float* a_dst = a_src + N;
    int*   seg   = (int*)(a_dst + N);    // N+1 ints

    node_dots<<<dim3((N + 3) / 4), dim3(256), 0, stream>>>(h, w, a_src, a_dst, N);
    seg_starts<<<dim3((N + 1 + 255) / 256), dim3(256), 0, stream>>>(dst, seg, N, E);
    gat_out<<<dim3((N + 3) / 4), dim3(256), 0, stream>>>(h, a_src, a_dst, src, seg, out, N);
}